// Round 13
// baseline (145.905 us; speedup 1.0000x reference)
//
#include <hip/hip_runtime.h>
#include <hip/hip_bf16.h>

#define IN_H  224
#define IN_W  224
#define OUT_H 218
#define OUT_W 218
#define NCH   64
#define PLANE (OUT_H * OUT_W)
#define TSTR  232        // tile row stride (floats): 8 rows staged
#define OCH   444        // obuf per-plane stride (436 data + 8 pad; 16g-word shift -> <=2-way banks)
#define NBLK  256        // 32n x 4mt x 2half = 8 XCDs x 32 -> 1 block/CU

typedef short bf16x8 __attribute__((ext_vector_type(8)));
typedef float f32x4  __attribute__((ext_vector_type(4)));

__device__ inline unsigned int f2bf(float f) {   // RNE f32 -> bf16 (cold path)
    unsigned int u = __builtin_bit_cast(unsigned int, f);
    return (u + 0x7fffu + ((u >> 16) & 1u)) >> 16;
}

// lgkm-only barrier: does NOT drain vmcnt, so global stores stay in flight
// across it (T3/T4). Rule #18: sched_barrier fences around the asm wait.
__device__ inline void bar_lgkm() {
    asm volatile("s_waitcnt lgkmcnt(0)" ::: "memory");
    __builtin_amdgcn_sched_barrier(0);
    __builtin_amdgcn_s_barrier();
    __builtin_amdgcn_sched_barrier(0);
}

// Pack weights into MFMA A-fragments (bf16, 7x7 zero-padded to 8x8). Verified R5-R12.
__global__ __launch_bounds__(512) void repack_w(const float* __restrict__ wgt,
                                                unsigned int* __restrict__ wa) {
    const int t    = threadIdx.x;
    const int lane = t & 63;
    const int fc   = t >> 6;
    const int mt   = fc >> 1, kt = fc & 1;
    const int ch   = 16 * mt + (lane & 15);
    const int dy   = 4 * kt + (lane >> 4);
    unsigned int w[4];
#pragma unroll
    for (int j = 0; j < 4; ++j) {
        float lo = (dy < 7 && 2 * j     < 7) ? wgt[ch * 49 + dy * 7 + 2 * j]     : 0.f;
        float hi = (dy < 7 && 2 * j + 1 < 7) ? wgt[ch * 49 + dy * 7 + 2 * j + 1] : 0.f;
        w[j] = f2bf(lo) | (f2bf(hi) << 16);
    }
    reinterpret_cast<uint4*>(wa)[fc * 64 + lane] = make_uint4(w[0], w[1], w[2], w[3]);
}

// Persistent block = (image n, 16-ch group mt, 110/108-row y-half), 512 thr,
// 1/CU. Loop over 2-row chunks: prefetch-to-reg next 8 input rows, compute
// 16ch x 2x218 into obuf, lgkm-barrier, store (vmem stays in flight),
// stage-write tile, lgkm-barrier. Stores never meet a vmcnt(0) barrier ->
// HBM drain overlaps the next chunk's compute (the R13 theory).
__global__ __launch_bounds__(512) void conv7x7_pipe(
    const float* __restrict__ in,
    const unsigned int* __restrict__ wa,
    float* __restrict__ out)
{
    __shared__ float tile[8 * TSTR];      //  7424 B: input rows y0..y0+7
    __shared__ float obuf[16 * OCH];      // 28416 B: 16 planes x 2x218 (+pad)

    const int tid  = threadIdx.x;
    const int lane = tid & 63;
    const int wid  = tid >> 6;
    const int g    = lane >> 4;
    const int c    = lane & 15;

    // rank: XCD k gets ranks [32k,32k+32) = 4 whole images (bid&7 = XCD).
    const int bid  = blockIdx.x;
    const int rank = (bid & 7) * 32 + (bid >> 3);
    const int n    = rank >> 3;
    const int rem  = rank & 7;
    const int mt   = rem >> 1;
    const int h    = rem & 1;
    const int nc   = h ? 54 : 55;         // chunks of 2 rows (110 / 108 split)
    const int yb   = h ? 110 : 0;

    // ---- stationary A-fragments ----
    union AB { uint4 u; bf16x8 v; };
    AB af[2];
    const uint4* wa4 = reinterpret_cast<const uint4*>(wa);
#pragma unroll
    for (int kt = 0; kt < 2; ++kt) af[kt].u = wa4[(mt * 2 + kt) * 64 + lane];

    const float* inb = in + (size_t)n * (IN_H * IN_W);

    // zero pad cols 224..231 once (stage never rewrites them)
    if (tid < 64) tile[(tid >> 3) * TSTR + 224 + (tid & 7)] = 0.f;

    // prologue: stage chunk 0's 8 rows (448 float4, one per thread tid<448)
    const int srow = tid / 56, scol = (tid % 56) * 4;   // valid when tid<448
    if (tid < 448) {
        float4 v = *reinterpret_cast<const float4*>(inb + min(yb + srow, IN_H - 1) * IN_W + scol);
        *reinterpret_cast<float4*>(&tile[srow * TSTR + scol]) = v;
    }
    __syncthreads();   // one full barrier at start is harmless (no stores yet)

    for (int k = 0; k < nc; ++k) {
        const int y0  = yb + 2 * k;
        const int y0n = yb + 2 * min(k + 1, nc - 1);

        // ---- T14 issue-early: prefetch next chunk's tile rows to registers ----
        float4 pre;
        if (tid < 448)
            pre = *reinterpret_cast<const float4*>(inb + min(y0n + srow, IN_H - 1) * IN_W + scol);

        // ---- compute: 28 (r in 0..1, strip s in 0..13) over 8 waves ----
        for (int kk = wid; kk < 28; kk += 8) {
            const int r  = kk / 14;
            const int x0 = 16 * (kk - 14 * r);

            AB bf[2];
#pragma unroll
            for (int kt = 0; kt < 2; ++kt) {
                // tile row r+4kt+g; index 8 (r=1,kt=1,g=3) meets only zero
                // weights -> clamp to 7 (finite data x 0 = 0).
                const int row = min(r + 4 * kt + g, 7);
                const float* rb = &tile[row * TSTR + x0 + c];
                union { unsigned int u[4]; uint4 q; } bb;
#pragma unroll
                for (int j = 0; j < 4; ++j) {
                    __hip_bfloat162 h2 =
                        __float22bfloat162_rn(make_float2(rb[2 * j], rb[2 * j + 1]));
                    unsigned int uw;
                    __builtin_memcpy(&uw, &h2, sizeof(uw));
                    bb.u[j] = uw;
                }
                bf[kt].u = bb.q;
            }

            f32x4 acc = {0.f, 0.f, 0.f, 0.f};
            acc = __builtin_amdgcn_mfma_f32_16x16x32_bf16(af[0].v, bf[0].v, acc, 0, 0, 0);
            acc = __builtin_amdgcn_mfma_f32_16x16x32_bf16(af[1].v, bf[1].v, acc, 0, 0, 0);

            if (x0 + c < OUT_W) {
#pragma unroll
                for (int rr = 0; rr < 4; ++rr)
                    obuf[(4 * g + rr) * OCH + r * OUT_W + x0 + c] = acc[rr];
            }
        }
        bar_lgkm();   // obuf complete; tile reads retired. Stores stay in flight.

        // ---- store: wave w -> planes 2w,2w+1; 2x218 f32 = 109 dwordx4 each,
        //      one contiguous 1744B run extending this block's plane stream ----
        {
            const size_t rowoff = (size_t)y0 * OUT_W;
#pragma unroll
            for (int i = 0; i < 2; ++i) {
                const int p = 2 * wid + i;
                const float* src = &obuf[p * OCH];
                float* dst = out + ((size_t)(n * NCH + 16 * mt + p)) * PLANE + rowoff;
#pragma unroll
                for (int j2 = 0; j2 < 2; ++j2) {
                    const int idx = lane + 64 * j2;
                    if (idx < 109)
                        *reinterpret_cast<float4*>(dst + 4 * idx) =
                            *reinterpret_cast<const float4*>(src + 4 * idx);
                }
            }
        }

        // ---- T14 write-late: stage next chunk's tile (compiler inserts the
        //      counted vmcnt wait for `pre` only) ----
        if (tid < 448)
            *reinterpret_cast<float4*>(&tile[srow * TSTR + scol]) = pre;
        bar_lgkm();   // tile ready for next chunk; store ds_reads retired.
    }
}

extern "C" void kernel_launch(void* const* d_in, const int* in_sizes, int n_in,
                              void* d_out, int out_size, void* d_ws, size_t ws_size,
                              hipStream_t stream) {
    const float* in  = (const float*)d_in[0];
    const float* wgt = (const float*)d_in[1];
    float* out = (float*)d_out;
    unsigned int* wa = (unsigned int*)d_ws;   // 8*64*16 = 8192 B

    repack_w<<<1, 512, 0, stream>>>(wgt, wa);
    conv7x7_pipe<<<NBLK, 512, 0, stream>>>(in, wa, out);
}

// Round 14
// 138.816 us; speedup vs baseline: 1.0511x; 1.0511x over previous
//
#include <hip/hip_runtime.h>
#include <hip/hip_bf16.h>

#define IN_H  224
#define IN_W  224
#define OUT_H 218
#define OUT_W 218
#define NCH   64
#define PLANE (OUT_H * OUT_W)
#define TSTR  232        // input ring row stride (floats)
#define OCH   220        // obuf per-plane stride (218 data + 2 pad)
#define NBLK  512        // 32n x 4mt x 4quarter = 8 XCDs x 64 -> all resident, 2/CU

typedef short bf16x8 __attribute__((ext_vector_type(8)));
typedef float f32x4  __attribute__((ext_vector_type(4)));

__device__ inline unsigned int f2bf(float f) {   // RNE f32 -> bf16 (cold path)
    unsigned int u = __builtin_bit_cast(unsigned int, f);
    return (u + 0x7fffu + ((u >> 16) & 1u)) >> 16;
}

// lgkm-only barrier: LDS ops retired, global stores stay in flight.
__device__ inline void bar_lgkm() {
    asm volatile("s_waitcnt lgkmcnt(0)" ::: "memory");
    __builtin_amdgcn_sched_barrier(0);
    __builtin_amdgcn_s_barrier();
    __builtin_amdgcn_sched_barrier(0);
}

// Pack weights into MFMA A-fragments (bf16, 7x7 zero-padded to 8x8). Verified R5-R13.
// [fc = mt*2+kt][lane]: ch = 16*mt + (lane&15), dy = 4*kt + (lane>>4),
// word j = {dx=2j (lo), dx=2j+1 (hi)}.
__global__ __launch_bounds__(512) void repack_w(const float* __restrict__ wgt,
                                                unsigned int* __restrict__ wa) {
    const int t    = threadIdx.x;
    const int lane = t & 63;
    const int fc   = t >> 6;
    const int mt   = fc >> 1, kt = fc & 1;
    const int ch   = 16 * mt + (lane & 15);
    const int dy   = 4 * kt + (lane >> 4);
    unsigned int w[4];
#pragma unroll
    for (int j = 0; j < 4; ++j) {
        float lo = (dy < 7 && 2 * j     < 7) ? wgt[ch * 49 + dy * 7 + 2 * j]     : 0.f;
        float hi = (dy < 7 && 2 * j + 1 < 7) ? wgt[ch * 49 + dy * 7 + 2 * j + 1] : 0.f;
        w[j] = f2bf(lo) | (f2bf(hi) << 16);
    }
    reinterpret_cast<uint4*>(wa)[fc * 64 + lane] = make_uint4(w[0], w[1], w[2], w[3]);
}

// Producer-consumer: block = (n, 16-ch group mt, ~55-row quarter). 8 waves:
// waves 0..6 compute chunk k (one output row, 14 strips) into obuf[k&1];
// wave 7 simultaneously drains obuf[(k-1)&1] to HBM. lgkm-only barrier per
// chunk. All vmcnt throttling lands on the store wave; compute never waits
// on HBM (R14 theory). Input rows live in an 8-slot ring (slot = row&7);
// the per-chunk stage writes only the slot the current chunk reads as
// dy=7 zero-weight garbage -> race-free (torn data finite x 0).
__global__ __launch_bounds__(512) void conv7x7_pc(
    const float* __restrict__ in,
    const unsigned int* __restrict__ wa,
    float* __restrict__ out)
{
    __shared__ float tile[8 * TSTR];        //  7424 B: 8-row input ring
    __shared__ float obuf[2][16 * OCH];     // 28160 B: dbuf, 1 row x 16 planes

    const int tid  = threadIdx.x;
    const int lane = tid & 63;
    const int wid  = tid >> 6;
    const int g    = lane >> 4;
    const int c    = lane & 15;

    // Chunked XCD map (bijective: 512 = 8*64): XCD k gets 4 whole images;
    // within an image: mt outer, y-quarter inner.
    const int bid  = blockIdx.x;
    const int rank = (bid & 7) * 64 + (bid >> 3);
    const int n    = rank >> 4;
    const int rem  = rank & 15;
    const int mt   = rem >> 2;
    const int q    = rem & 3;
    const int y0   = (q <= 1) ? 55 * q : 110 + 54 * (q - 2);
    const int nc   = (q <= 1) ? 55 : 54;

    // ---- stationary A-fragments ----
    union AB { uint4 u; bf16x8 v; };
    AB af[2];
    const uint4* wa4 = reinterpret_cast<const uint4*>(wa);
#pragma unroll
    for (int kt = 0; kt < 2; ++kt) af[kt].u = wa4[(mt * 2 + kt) * 64 + lane];

    const float* inb = in + (size_t)n * (IN_H * IN_W);

    // zero pad cols 224..231 of all 8 ring slots (never rewritten)
    if (tid < 64) tile[(tid >> 3) * TSTR + 224 + (tid & 7)] = 0.f;

    // prologue: stage rows y0..y0+6 into their ring slots
    for (int idx = tid; idx < 7 * 112; idx += 512) {
        int d = idx / 112, c2 = idx - d * 112;
        int row = y0 + d;
        float2 v = *reinterpret_cast<const float2*>(inb + row * IN_W + 2 * c2);
        float* t = &tile[(row & 7) * TSTR + 2 * c2];
        t[0] = v.x; t[1] = v.y;
    }
    __syncthreads();   // full barrier fine here (no stores in flight yet)

    const size_t obase = ((size_t)(n * NCH + 16 * mt)) * PLANE;

    for (int k = 0; k < nc; ++k) {
        const int yk = y0 + k;
        if (wid < 7) {
            // stage row yk+7 into slot (yk+7)&7 — this chunk reads that slot
            // only as dy=7 (zero weights); future chunks read it as real.
            if (tid < 112) {
                const int srow = yk + 7;
                const int crow = min(srow, IN_H - 1);
                float2 v = *reinterpret_cast<const float2*>(inb + crow * IN_W + 2 * tid);
                float* t = &tile[(srow & 7) * TSTR + 2 * tid];
                t[0] = v.x; t[1] = v.y;
            }

            // compute 14 strips (2 per wave) into obuf[k&1]
            float* ob = obuf[k & 1];
#pragma unroll
            for (int t2 = 0; t2 < 2; ++t2) {
                const int x0 = 16 * (wid + 7 * t2);

                AB bf[2];
#pragma unroll
                for (int kt = 0; kt < 2; ++kt) {
                    const int srow2 = yk + 4 * kt + g;   // dy = 4kt+g
                    const float* rb = &tile[(srow2 & 7) * TSTR + x0 + c];
                    union { unsigned int u[4]; uint4 qq; } bb;
#pragma unroll
                    for (int j = 0; j < 4; ++j) {
                        __hip_bfloat162 h2 =
                            __float22bfloat162_rn(make_float2(rb[2 * j], rb[2 * j + 1]));
                        unsigned int uw;
                        __builtin_memcpy(&uw, &h2, sizeof(uw));
                        bb.u[j] = uw;
                    }
                    bf[kt].u = bb.qq;
                }

                f32x4 acc = {0.f, 0.f, 0.f, 0.f};
                acc = __builtin_amdgcn_mfma_f32_16x16x32_bf16(af[0].v, bf[0].v, acc, 0, 0, 0);
                acc = __builtin_amdgcn_mfma_f32_16x16x32_bf16(af[1].v, bf[1].v, acc, 0, 0, 0);

                if (x0 + c < OUT_W) {
#pragma unroll
                    for (int rr = 0; rr < 4; ++rr)
                        ob[(4 * g + rr) * OCH + x0 + c] = acc[rr];
                }
            }
        } else if (k > 0) {
            // store wave: drain chunk k-1 (one row x 16 planes, float2 = 8B-aligned)
            const float* src = obuf[(k - 1) & 1];
            const size_t rowoff = (size_t)(yk - 1) * OUT_W;
#pragma unroll
            for (int p = 0; p < 16; ++p) {
                float* dst = out + obase + (size_t)p * PLANE + rowoff;
                const float* sp = src + p * OCH;
#pragma unroll
                for (int j = 0; j < 2; ++j) {
                    const int idx = lane + 64 * j;
                    if (idx < 109)
                        *reinterpret_cast<float2*>(dst + 2 * idx) =
                            *reinterpret_cast<const float2*>(sp + 2 * idx);
                }
            }
        }
        bar_lgkm();   // obuf[k&1] visible; store-reads of obuf[(k-1)&1] retired
    }

    // epilogue: drain the last chunk
    if (wid == 7) {
        const float* src = obuf[(nc - 1) & 1];
        const size_t rowoff = (size_t)(y0 + nc - 1) * OUT_W;
#pragma unroll
        for (int p = 0; p < 16; ++p) {
            float* dst = out + obase + (size_t)p * PLANE + rowoff;
            const float* sp = src + p * OCH;
#pragma unroll
            for (int j = 0; j < 2; ++j) {
                const int idx = lane + 64 * j;
                if (idx < 109)
                    *reinterpret_cast<float2*>(dst + 2 * idx) =
                        *reinterpret_cast<const float2*>(sp + 2 * idx);
            }
        }
    }
}

extern "C" void kernel_launch(void* const* d_in, const int* in_sizes, int n_in,
                              void* d_out, int out_size, void* d_ws, size_t ws_size,
                              hipStream_t stream) {
    const float* in  = (const float*)d_in[0];
    const float* wgt = (const float*)d_in[1];
    float* out = (float*)d_out;
    unsigned int* wa = (unsigned int*)d_ws;   // 8*64*16 = 8192 B

    repack_w<<<1, 512, 0, stream>>>(wgt, wa);
    conv7x7_pc<<<NBLK, 512, 0, stream>>>(in, wa, out);
}

// Round 15
// 127.410 us; speedup vs baseline: 1.1452x; 1.0895x over previous
//
#include <hip/hip_runtime.h>
#include <hip/hip_bf16.h>

#define IN_H  224
#define IN_W  224
#define OUT_H 218
#define OUT_W 218
#define NCH   64
#define PLANE (OUT_H * OUT_W)
#define TSTR  232        // ring row stride (floats)
#define OCH2  444        // obuf plane stride: 436 data + 8 pad (16B-aligned, 2-way banks)
#define NBLK  512        // 32n x 4mt x 4quarter = 8 XCDs x 64; 2 blocks/CU

typedef short bf16x8 __attribute__((ext_vector_type(8)));
typedef float f32x4  __attribute__((ext_vector_type(4)));

__device__ inline unsigned int f2bf(float f) {   // RNE f32 -> bf16 (cold path)
    unsigned int u = __builtin_bit_cast(unsigned int, f);
    return (u + 0x7fffu + ((u >> 16) & 1u)) >> 16;
}

// lgkm-only barrier: LDS ops retired; global stores stay in flight (no vmcnt).
__device__ inline void bar_lgkm() {
    asm volatile("s_waitcnt lgkmcnt(0)" ::: "memory");
    __builtin_amdgcn_sched_barrier(0);
    __builtin_amdgcn_s_barrier();
    __builtin_amdgcn_sched_barrier(0);
}

// Pack weights into MFMA A-fragments (bf16, 7x7 zero-padded to 8x8). Verified R5-R14.
// [fc = mt*2+kt][lane]: ch = 16*mt + (lane&15), dy = 4*kt + (lane>>4),
// word j = {dx=2j (lo), dx=2j+1 (hi)}.
__global__ __launch_bounds__(512) void repack_w(const float* __restrict__ wgt,
                                                unsigned int* __restrict__ wa) {
    const int t    = threadIdx.x;
    const int lane = t & 63;
    const int fc   = t >> 6;
    const int mt   = fc >> 1, kt = fc & 1;
    const int ch   = 16 * mt + (lane & 15);
    const int dy   = 4 * kt + (lane >> 4);
    unsigned int w[4];
#pragma unroll
    for (int j = 0; j < 4; ++j) {
        float lo = (dy < 7 && 2 * j     < 7) ? wgt[ch * 49 + dy * 7 + 2 * j]     : 0.f;
        float hi = (dy < 7 && 2 * j + 1 < 7) ? wgt[ch * 49 + dy * 7 + 2 * j + 1] : 0.f;
        w[j] = f2bf(lo) | (f2bf(hi) << 16);
    }
    reinterpret_cast<uint4*>(wa)[fc * 64 + lane] = make_uint4(w[0], w[1], w[2], w[3]);
}

// Persistent block = (image n, 16-ch group mt, ~55-row quarter). Waves 0-3
// compute chunk k (2 output rows) into obuf[k&1] + prefetch input; waves 4-7
// drain obuf[(k-1)&1] to HBM as 1744B runs extending per-plane streams.
// Two lgkm-only barriers per chunk; vmcnt throttling sits on store waves only.
__global__ __launch_bounds__(512) void conv7x7_ps(
    const float* __restrict__ in,
    const unsigned int* __restrict__ wa,
    float* __restrict__ out)
{
    __shared__ float tile[8 * TSTR];        //  7424 B: 8-row input ring (slot=row&7)
    __shared__ float obuf[2][16 * OCH2];    // 56832 B: dbuf, 16 planes x 2x218

    const int tid  = threadIdx.x;
    const int lane = tid & 63;
    const int wid  = tid >> 6;
    const int g    = lane >> 4;
    const int c    = lane & 15;

    // Chunked XCD map (bijective: 512 = 8*64): XCD x gets images [4x,4x+4);
    // within an image all (mt,q) pieces stay on the same XCD (input L2 reuse).
    const int bid  = blockIdx.x;
    const int rank = (bid & 7) * 64 + (bid >> 3);
    const int n    = rank >> 4;
    const int rem  = rank & 15;
    const int mt   = rem >> 2;
    const int q    = rem & 3;
    const int y0   = q ? (56 + 54 * (q - 1)) : 0;   // 0,56,110,164
    const int nc   = q ? 27 : 28;                   // 2-row chunks

    // ---- stationary A-fragments ----
    union AB { uint4 u; bf16x8 v; };
    AB af[2];
    const uint4* wa4 = reinterpret_cast<const uint4*>(wa);
#pragma unroll
    for (int kt = 0; kt < 2; ++kt) af[kt].u = wa4[(mt * 2 + kt) * 64 + lane];

    const float* inb = in + (size_t)n * (IN_H * IN_W);
    const size_t obase = ((size_t)(n * NCH + 16 * mt)) * PLANE;

    // zero pad cols 224..231 of all 8 ring slots (never rewritten)
    if (tid < 64) tile[(tid >> 3) * TSTR + 224 + (tid & 7)] = 0.f;

    // prologue: stage rows y0..y0+7 into ring slots
    for (int idx = tid; idx < 8 * 112; idx += 512) {
        int d = idx / 112, c2 = idx - d * 112;
        int row = y0 + d;
        float2 v = *reinterpret_cast<const float2*>(inb + min(row, IN_H - 1) * IN_W + 2 * c2);
        *reinterpret_cast<float2*>(&tile[(row & 7) * TSTR + 2 * c2]) = v;
    }
    __syncthreads();   // no global stores in flight yet

    const bool isComp = (wid < 4);
    float2 pre = make_float2(0.f, 0.f);   // prefetch register (compute waves, tid<224)
    const int prr = (tid >= 112);         // prefetch row select
    const int pcol = 2 * (tid - 112 * prr);

    for (int k = 0; k < nc; ++k) {
        // (1) stage-write rows y0+2k+6, y0+2k+7 (prefetched during chunk k-1).
        //     Their ring slots held rows y0+2k-2/-1, dead for chunk k (which
        //     needs real rows >= y0+2k; aliased reads are dy=7 zero-weight).
        if (isComp && k > 0 && tid < 224) {
            const int row = y0 + 2 * k + 6 + prr;
            *reinterpret_cast<float2*>(&tile[(row & 7) * TSTR + pcol]) = pre;
        }
        bar_lgkm();

        if (isComp) {
            // (2) issue prefetch loads for chunk k+1 (rows y0+2k+8, +9)
            if (k + 1 < nc && tid < 224) {
                const int row = min(y0 + 2 * k + 8 + prr, IN_H - 1);
                pre = *reinterpret_cast<const float2*>(inb + row * IN_W + pcol);
            }
            // (3) compute 28 (r,strip) iters over 4 waves into obuf[k&1]
            float* ob = obuf[k & 1];
            for (int k2 = wid; k2 < 28; k2 += 4) {
                const int r  = k2 / 14;
                const int x0 = 16 * (k2 - 14 * r);

                AB bf[2];
#pragma unroll
                for (int kt = 0; kt < 2; ++kt) {
                    const int row = y0 + 2 * k + r + 4 * kt + g;  // slot read; overflow row
                    const float* rb = &tile[(row & 7) * TSTR + x0 + c];  // aliases = zero-weight
                    union { unsigned int u[4]; uint4 qq; } bb;
#pragma unroll
                    for (int j = 0; j < 4; ++j) {
                        __hip_bfloat162 h2 =
                            __float22bfloat162_rn(make_float2(rb[2 * j], rb[2 * j + 1]));
                        unsigned int uw;
                        __builtin_memcpy(&uw, &h2, sizeof(uw));
                        bb.u[j] = uw;
                    }
                    bf[kt].u = bb.qq;
                }

                f32x4 acc = {0.f, 0.f, 0.f, 0.f};
                acc = __builtin_amdgcn_mfma_f32_16x16x32_bf16(af[0].v, bf[0].v, acc, 0, 0, 0);
                acc = __builtin_amdgcn_mfma_f32_16x16x32_bf16(af[1].v, bf[1].v, acc, 0, 0, 0);

                if (x0 + c < OUT_W) {
#pragma unroll
                    for (int rr = 0; rr < 4; ++rr)
                        ob[(4 * g + rr) * OCH2 + r * OUT_W + x0 + c] = acc[rr];
                }
            }
        } else if (k > 0) {
            // (4) store chunk k-1: 4 planes/wave, each 2x218 f32 = 109 dwordx4,
            //     contiguous run extending this block's per-plane stream.
            const float* src = obuf[(k - 1) & 1];
            const int w4 = wid - 4;
            const size_t rowoff = (size_t)(y0 + 2 * (k - 1)) * OUT_W;
#pragma unroll
            for (int i = 0; i < 4; ++i) {
                const int p = 4 * w4 + i;
                float* dst = out + obase + (size_t)p * PLANE + rowoff;
                const float* sp = src + p * OCH2;
#pragma unroll
                for (int j = 0; j < 2; ++j) {
                    const int idx = lane + 64 * j;
                    if (idx < 109)
                        *reinterpret_cast<float4*>(dst + 4 * idx) =
                            *reinterpret_cast<const float4*>(sp + 4 * idx);
                }
            }
        }
        bar_lgkm();
    }

    // epilogue: drain the last chunk
    if (!isComp) {
        const float* src = obuf[(nc - 1) & 1];
        const int w4 = wid - 4;
        const size_t rowoff = (size_t)(y0 + 2 * (nc - 1)) * OUT_W;
#pragma unroll
        for (int i = 0; i < 4; ++i) {
            const int p = 4 * w4 + i;
            float* dst = out + obase + (size_t)p * PLANE + rowoff;
            const float* sp = src + p * OCH2;
#pragma unroll
            for (int j = 0; j < 2; ++j) {
                const int idx = lane + 64 * j;
                if (idx < 109)
                    *reinterpret_cast<float4*>(dst + 4 * idx) =
                        *reinterpret_cast<const float4*>(sp + 4 * idx);
            }
        }
    }
}

extern "C" void kernel_launch(void* const* d_in, const int* in_sizes, int n_in,
                              void* d_out, int out_size, void* d_ws, size_t ws_size,
                              hipStream_t stream) {
    const float* in  = (const float*)d_in[0];
    const float* wgt = (const float*)d_in[1];
    float* out = (float*)d_out;
    unsigned int* wa = (unsigned int*)d_ws;   // 8*64*16 = 8192 B

    repack_w<<<1, 512, 0, stream>>>(wgt, wa);
    conv7x7_ps<<<NBLK, 512, 0, stream>>>(in, wa, out);
}

// Round 16
// 94.703 us; speedup vs baseline: 1.5407x; 1.3454x over previous
//
#include <hip/hip_runtime.h>
#include <hip/hip_bf16.h>

#define IN_H  224
#define IN_W  224
#define OUT_H 218
#define OUT_W 218
#define NCH   64
#define PLANE (OUT_H * OUT_W)
#define TSTR  232            // input tile row stride (floats)
#define NROW  2              // output rows per block
#define NYB   109            // 218/2
#define NMT   4              // channel groups of 16
#define OCH   440            // obuf plane stride: 436 data + 4 pad
#define NBLK  (32 * NMT * NYB)   // 13952 = 8 XCDs * 1744 -> bijective chunk map

typedef short bf16x8 __attribute__((ext_vector_type(8)));
typedef float f32x4  __attribute__((ext_vector_type(4)));

__device__ inline unsigned int f2bf(float f) {   // RNE f32 -> bf16 (cold path)
    unsigned int u = __builtin_bit_cast(unsigned int, f);
    return (u + 0x7fffu + ((u >> 16) & 1u)) >> 16;
}

// Pack weights into MFMA A-fragments (bf16, 7x7 zero-padded to 8x8). Verified R5-R15.
// [fc = mt*2+kt][lane]: ch = 16*mt + (lane&15), dy = 4*kt + (lane>>4),
// word j = {dx=2j (lo), dx=2j+1 (hi)}.
__global__ __launch_bounds__(512) void repack_w(const float* __restrict__ wgt,
                                                unsigned int* __restrict__ wa) {
    const int t    = threadIdx.x;
    const int lane = t & 63;
    const int fc   = t >> 6;
    const int mt   = fc >> 1, kt = fc & 1;
    const int ch   = 16 * mt + (lane & 15);
    const int dy   = 4 * kt + (lane >> 4);
    unsigned int w[4];
#pragma unroll
    for (int j = 0; j < 4; ++j) {
        float lo = (dy < 7 && 2 * j     < 7) ? wgt[ch * 49 + dy * 7 + 2 * j]     : 0.f;
        float hi = (dy < 7 && 2 * j + 1 < 7) ? wgt[ch * 49 + dy * 7 + 2 * j + 1] : 0.f;
        w[j] = f2bf(lo) | (f2bf(hi) << 16);
    }
    reinterpret_cast<uint4*>(wa)[fc * 64 + lane] = make_uint4(w[0], w[1], w[2], w[3]);
}

// Small independent block = (image n, FULL 16-ch group mt, 2 rows), 256 thr,
// 35.6KB LDS -> 4 blocks/CU. One chunk per block: stage -> compute (all 16
// channels kept, no duplicated work - the R10 bug) -> sync -> store 1744B
// runs -> exit. 4 naturally staggered blocks/CU overlap compute with drain
// without any barrier tricks (R16 theory).
__global__ __launch_bounds__(256) void conv7x7_sb(
    const float* __restrict__ in,
    const unsigned int* __restrict__ wa,
    float* __restrict__ out)
{
    __shared__ float tile[8 * TSTR];      //  7424 B: input rows y0..y0+7 (+zero pad)
    __shared__ float obuf[16 * OCH];      // 28160 B: 16 planes x (2 rows x 218)

    const int tid  = threadIdx.x;
    const int lane = tid & 63;
    const int wid  = tid >> 6;            // 0..3
    const int g    = lane >> 4;           // k-group -> dy / channel sub-row
    const int c    = lane & 15;           // pixel-in-group

    // Chunked XCD map (bijective: 13952 = 8*1744): XCD k gets 4 whole images,
    // y-innermost so consecutive ranks extend the same planes' runs.
    const int bid  = blockIdx.x;
    const int rank = (bid & 7) * (NBLK / 8) + (bid >> 3);
    const int n    = rank / (NMT * NYB);
    const int rem  = rank - n * (NMT * NYB);
    const int mt   = rem / NYB;
    const int yb   = rem - mt * NYB;
    const int y0   = yb * NROW;           // <= 216

    // ---- stationary A-fragments for this channel group ----
    union AB { uint4 u; bf16x8 v; };
    AB af[2];
    const uint4* wa4 = reinterpret_cast<const uint4*>(wa);
#pragma unroll
    for (int kt = 0; kt < 2; ++kt) af[kt].u = wa4[(mt * 2 + kt) * 64 + lane];

    // ---- stage 8 input rows (clamped at image bottom) ----
    const float* inb = in + (size_t)n * (IN_H * IN_W);
    for (int idx = tid; idx < 8 * 116; idx += 256) {
        int r = idx / 116, c2 = idx - r * 116;
        int iny = min(y0 + r, IN_H - 1);
        float2 v = (c2 < 112) ? *reinterpret_cast<const float2*>(inb + iny * IN_W + 2 * c2)
                              : make_float2(0.f, 0.f);   // zero pad cols 224..231
        tile[r * TSTR + 2 * c2]     = v.x;
        tile[r * TSTR + 2 * c2 + 1] = v.y;
    }
    __syncthreads();

    // ---- compute: 28 (row r, strip s) pairs over 4 waves = 7 each ----
    for (int k = wid; k < 2 * 14; k += 4) {
        const int r  = k / 14;
        const int x0 = 16 * (k - 14 * r);

        AB bf[2];
#pragma unroll
        for (int kt = 0; kt < 2; ++kt) {
            // tile row r+4kt+g; index 8 (r=1,kt=1,g=3) carries only zero
            // weights -> clamp to 7 (finite data x 0 = 0).
            const int row = min(r + 4 * kt + g, 7);
            const float* rb = &tile[row * TSTR + x0 + c];
            union { unsigned int u[4]; uint4 q; } bb;
#pragma unroll
            for (int j = 0; j < 4; ++j) {
                __hip_bfloat162 h2 =
                    __float22bfloat162_rn(make_float2(rb[2 * j], rb[2 * j + 1]));
                unsigned int uw;
                __builtin_memcpy(&uw, &h2, sizeof(uw));
                bb.u[j] = uw;
            }
            bf[kt].u = bb.q;
        }

        f32x4 acc = {0.f, 0.f, 0.f, 0.f};
        acc = __builtin_amdgcn_mfma_f32_16x16x32_bf16(af[0].v, bf[0].v, acc, 0, 0, 0);
        acc = __builtin_amdgcn_mfma_f32_16x16x32_bf16(af[1].v, bf[1].v, acc, 0, 0, 0);

        // obuf[plane=4g+rr][row r][col]; mask col>=218
        if (x0 + c < OUT_W) {
#pragma unroll
            for (int rr = 0; rr < 4; ++rr)
                obuf[(4 * g + rr) * OCH + r * OUT_W + x0 + c] = acc[rr];
        }
    }
    __syncthreads();

    // ---- store: wave w -> planes 4w..4w+3; each plane one 1744B contiguous
    //      16B-aligned run = 109 dwordx4, extending this plane's stream ----
    const size_t base = ((size_t)(n * NCH + 16 * mt)) * PLANE + (size_t)y0 * OUT_W;
#pragma unroll
    for (int i = 0; i < 4; ++i) {
        const int p = 4 * wid + i;
        const float* src = &obuf[p * OCH];
        float* dst = out + base + (size_t)p * PLANE;
#pragma unroll
        for (int j = 0; j < 2; ++j) {
            int idx = 64 * j + lane;
            if (idx < 109)
                *reinterpret_cast<float4*>(dst + 4 * idx) =
                    *reinterpret_cast<const float4*>(src + 4 * idx);
        }
    }
}

extern "C" void kernel_launch(void* const* d_in, const int* in_sizes, int n_in,
                              void* d_out, int out_size, void* d_ws, size_t ws_size,
                              hipStream_t stream) {
    const float* in  = (const float*)d_in[0];
    const float* wgt = (const float*)d_in[1];
    float* out = (float*)d_out;
    unsigned int* wa = (unsigned int*)d_ws;   // 8*64*16 = 8192 B

    repack_w<<<1, 512, 0, stream>>>(wgt, wa);
    conv7x7_sb<<<NBLK, 256, 0, stream>>>(in, wa, out);
}

// Round 17
// 86.721 us; speedup vs baseline: 1.6825x; 1.0920x over previous
//
#include <hip/hip_runtime.h>
#include <hip/hip_bf16.h>

#define IN_H  224
#define IN_W  224
#define OUT_H 218
#define OUT_W 218
#define NCH   64
#define PLANE (OUT_H * OUT_W)
#define RSH   464            // bf16 tile row stride (ushorts): 232 dwords, %32=8
#define CP1   232            // copy1 offset within row (ushorts): +116 dwords, %32=20
#define NROW  4              // output rows per block
#define NYB   55             // ceil(218/4)
#define NMT   4              // channel groups of 16
#define OCH   876            // obuf per-plane stride (872 data + 4 pad)
#define NBLK  (32 * NMT * NYB)   // 7040 = 8 XCDs * 880 -> bijective chunk map

typedef short bf16x8 __attribute__((ext_vector_type(8)));
typedef float f32x4  __attribute__((ext_vector_type(4)));

__device__ inline unsigned int f2bf(float f) {   // RNE f32 -> bf16 (cold path)
    unsigned int u = __builtin_bit_cast(unsigned int, f);
    return (u + 0x7fffu + ((u >> 16) & 1u)) >> 16;
}

__device__ inline unsigned int pk2(float lo, float hi) {  // v_cvt_pk path (R12-proven)
    __hip_bfloat162 h2 = __float22bfloat162_rn(make_float2(lo, hi));
    unsigned int u;
    __builtin_memcpy(&u, &h2, sizeof(u));
    return u;
}

// Pack weights into MFMA A-fragments (bf16, 7x7 zero-padded to 8x8). Verified R5-R16.
// [fc = mt*2+kt][lane]: ch = 16*mt + (lane&15), dy = 4*kt + (lane>>4),
// word j = {dx=2j (lo), dx=2j+1 (hi)}.
__global__ __launch_bounds__(512) void repack_w(const float* __restrict__ wgt,
                                                unsigned int* __restrict__ wa) {
    const int t    = threadIdx.x;
    const int lane = t & 63;
    const int fc   = t >> 6;
    const int mt   = fc >> 1, kt = fc & 1;
    const int ch   = 16 * mt + (lane & 15);
    const int dy   = 4 * kt + (lane >> 4);
    unsigned int w[4];
#pragma unroll
    for (int j = 0; j < 4; ++j) {
        float lo = (dy < 7 && 2 * j     < 7) ? wgt[ch * 49 + dy * 7 + 2 * j]     : 0.f;
        float hi = (dy < 7 && 2 * j + 1 < 7) ? wgt[ch * 49 + dy * 7 + 2 * j + 1] : 0.f;
        w[j] = f2bf(lo) | (f2bf(hi) << 16);
    }
    reinterpret_cast<uint4*>(wa)[fc * 64 + lane] = make_uint4(w[0], w[1], w[2], w[3]);
}

// R12 structure (proven 89.1us) + bf16 dual-copy tile: stage converts f32->bf16
// ONCE; B-build is 4 aligned dword LDS reads per kt (no cvt, half the traffic).
// copy0 = natural order, copy1[s] = elem[s+1]; lane uses copy (c&1) at even
// element start x0+c-(c&1).
__global__ __launch_bounds__(512) void conv7x7_row(
    const float* __restrict__ in,
    const unsigned int* __restrict__ wa,
    float* __restrict__ out)
{
    __shared__ unsigned short tbf[10 * RSH];  //  9280 B: bf16 rows y0..y0+9, 2 copies
    __shared__ float obuf[16 * OCH];          // 56064 B: 16 planes x (4 rows x 218)

    const int tid  = threadIdx.x;
    const int lane = tid & 63;
    const int wid  = tid >> 6;
    const int g    = lane >> 4;           // k-group -> dy / channel sub-row
    const int c    = lane & 15;           // pixel-in-group

    // Chunked XCD map (bijective: 7040 = 8*880): XCD k gets 4 whole images,
    // y-innermost so adjacent ranks extend the same planes' runs.
    const int bid  = blockIdx.x;
    const int rank = (bid & 7) * (NBLK / 8) + (bid >> 3);
    const int n    = rank / (NMT * NYB);
    const int rem  = rank - n * (NMT * NYB);
    const int mt   = rem / NYB;
    const int yb   = rem - mt * NYB;
    const int y0   = yb * NROW;           // <= 216

    // ---- stationary A-fragments for this channel group ----
    union AB { uint4 u; bf16x8 v; };
    AB af[2];
    const uint4* wa4 = reinterpret_cast<const uint4*>(wa);
#pragma unroll
    for (int kt = 0; kt < 2; ++kt) af[kt].u = wa4[(mt * 2 + kt) * 64 + lane];

    // ---- stage 10 input rows as bf16 dual-copy (clamped at image bottom;
    //      clamped rows feed only outputs y>=218 which are never stored) ----
    const float* inb = in + (size_t)n * (IN_H * IN_W);
    for (int idx = tid; idx < 10 * 112; idx += 512) {
        int r = idx / 112, c2 = idx - r * 112;          // elements 2c2, 2c2+1
        int iny = min(y0 + r, IN_H - 1);
        const float* rp = inb + iny * IN_W + 2 * c2;
        float2 v = *reinterpret_cast<const float2*>(rp);
        float nx = (c2 < 111) ? rp[2] : 0.f;            // neighbor elem 2c2+2 (pad=0)
        // copy0 slots (2c2,2c2+1) = elems (2c2,2c2+1)
        *reinterpret_cast<unsigned int*>(&tbf[r * RSH + 2 * c2]) = pk2(v.x, v.y);
        // copy1 slots (2c2,2c2+1) = elems (2c2+1,2c2+2)
        *reinterpret_cast<unsigned int*>(&tbf[r * RSH + CP1 + 2 * c2]) = pk2(v.y, nx);
    }
    // zero pad slots 224..231 of both copies (reads reach slot 229)
    for (int idx = tid; idx < 10 * 8; idx += 512) {
        int r = idx >> 3, j = idx & 7;                  // j: 4 uints per copy
        *reinterpret_cast<unsigned int*>(&tbf[r * RSH + (j >> 2) * CP1 + 224 + 2 * (j & 3)]) = 0u;
    }
    __syncthreads();

    // ---- compute: 56 (row r, strip s) pairs over 8 waves = 7 each ----
    const int sh = c & 1;
    for (int k = wid; k < 4 * 14; k += 8) {
        const int r  = k / 14;
        const int x0 = 16 * (k - 14 * r);
        const int e0 = x0 + c - sh;       // even element start

        AB bf[2];
#pragma unroll
        for (int kt = 0; kt < 2; ++kt) {
            // row r+4kt+g; index 10 (only r=3,kt=1,g=3) carries zero weights ->
            // clamp to 9 (finite data x 0 = 0).
            const int row = min(r + 4 * kt + g, 9);
            const unsigned int* p = reinterpret_cast<const unsigned int*>(
                &tbf[row * RSH + sh * CP1 + e0]);
            union { unsigned int u[4]; uint4 q; } bb;
            bb.u[0] = p[0]; bb.u[1] = p[1]; bb.u[2] = p[2]; bb.u[3] = p[3];
            bf[kt].u = bb.q;
        }

        f32x4 acc = {0.f, 0.f, 0.f, 0.f};
        acc = __builtin_amdgcn_mfma_f32_16x16x32_bf16(af[0].v, bf[0].v, acc, 0, 0, 0);
        acc = __builtin_amdgcn_mfma_f32_16x16x32_bf16(af[1].v, bf[1].v, acc, 0, 0, 0);

        // obuf[plane=4g+rr][row r][col]; mask col>=218
        if (x0 + c < OUT_W) {
#pragma unroll
            for (int rr = 0; rr < 4; ++rr)
                obuf[(4 * g + rr) * OCH + r * OUT_W + x0 + c] = acc[rr];
        }
    }
    __syncthreads();

    // ---- store: wave w -> planes 2w,2w+1; each plane one 3488B contiguous
    //      16B-aligned run = 218 dwordx4 (109 for the 2-row tail block) ----
    const int vrows = min(NROW, OUT_H - y0);
    const int nf4   = (vrows * OUT_W) >> 2;        // 218 or 109
    const size_t base = ((size_t)(n * NCH + 16 * mt)) * PLANE + (size_t)y0 * OUT_W;
#pragma unroll
    for (int i = 0; i < 2; ++i) {
        const int p = 2 * wid + i;
        const float* src = &obuf[p * OCH];
        float* dst = out + base + (size_t)p * PLANE;
#pragma unroll
        for (int j = 0; j < 4; ++j) {
            int idx = 64 * j + lane;
            if (idx < nf4)
                *reinterpret_cast<float4*>(dst + 4 * idx) =
                    *reinterpret_cast<const float4*>(src + 4 * idx);
        }
    }
}

extern "C" void kernel_launch(void* const* d_in, const int* in_sizes, int n_in,
                              void* d_out, int out_size, void* d_ws, size_t ws_size,
                              hipStream_t stream) {
    const float* in  = (const float*)d_in[0];
    const float* wgt = (const float*)d_in[1];
    float* out = (float*)d_out;
    unsigned int* wa = (unsigned int*)d_ws;   // 8*64*16 = 8192 B

    repack_w<<<1, 512, 0, stream>>>(wgt, wa);
    conv7x7_row<<<NBLK, 512, 0, stream>>>(in, wa, out);
}